// Round 1
// baseline (14.739 us; speedup 1.0000x reference)
//
#include <hip/hip_runtime.h>

// x: (16, 48, 10, 128, 128) f32.  out: (16, 10, 128, 128) f32.
// out[b,k,h,w] = p_k * LA(b,h,w) + q_k * x[b,47,0,h,w]
// LA = (1-mu)^48 * mean_t(x_t) + mu * sum_t (1-mu)^(47-t) x_t   (feature 0 only)

#define NB 16
#define NT 48
#define NF 10
#define HW (128 * 128)
#define NK 10

struct Coefs {
    float w[NT];
    float p[NK];
    float q[NK];
};

constexpr Coefs make_coefs() {
    Coefs c{};
    const double mu = 2.0 / 11.0;
    const double om = 1.0 - mu;
    double pow48 = 1.0;
    for (int i = 0; i < NT; ++i) pow48 *= om;
    for (int t = 0; t < NT; ++t) {
        double e = 1.0;
        for (int i = 0; i < NT - 1 - t; ++i) e *= om;   // (1-mu)^(47-t)
        c.w[t] = (float)(pow48 / (double)NT + mu * e);
    }
    // a_{-1}=x47 (p=-0,q=1), a_0=LA (p=1,q=0); a_{k+1}=mu*a_{k-1}+(1-mu)*a_k
    double pm1 = 0.0, p0 = 1.0, qm1 = 1.0, q0 = 0.0;
    for (int k = 0; k < NK; ++k) {
        c.p[k] = (float)p0;
        c.q[k] = (float)q0;
        double pn = mu * pm1 + om * p0;
        double qn = mu * qm1 + om * q0;
        pm1 = p0; p0 = pn;
        qm1 = q0; q0 = qn;
    }
    return c;
}

constexpr Coefs CO = make_coefs();

__global__ __launch_bounds__(256) void ema_kernel(const float* __restrict__ x,
                                                  float* __restrict__ out) {
    const int tid = blockIdx.x * blockDim.x + threadIdx.x;  // over NB * HW/2
    const int PPB = HW / 2;                                 // float2 chunks per plane
    const int b   = tid / PPB;
    const int c2  = tid - b * PPB;

    // feature-0 plane of batch b, time t starts at b*NT*NF*HW + t*NF*HW
    const float2* xp =
        reinterpret_cast<const float2*>(x + (size_t)b * NT * NF * HW) + c2;

    float2 la  = make_float2(0.f, 0.f);
    float2 x47 = make_float2(0.f, 0.f);
#pragma unroll
    for (int t = 0; t < NT; ++t) {
        float2 v = xp[(size_t)t * (NF * HW / 2)];
        la.x = fmaf(CO.w[t], v.x, la.x);
        la.y = fmaf(CO.w[t], v.y, la.y);
        if (t == NT - 1) x47 = v;
    }

    float2* op = reinterpret_cast<float2*>(out + (size_t)b * NK * HW) + c2;
#pragma unroll
    for (int k = 0; k < NK; ++k) {
        float2 o;
        o.x = fmaf(CO.p[k], la.x, CO.q[k] * x47.x);
        o.y = fmaf(CO.p[k], la.y, CO.q[k] * x47.y);
        op[(size_t)k * (HW / 2)] = o;
    }
}

extern "C" void kernel_launch(void* const* d_in, const int* in_sizes, int n_in,
                              void* d_out, int out_size, void* d_ws, size_t ws_size,
                              hipStream_t stream) {
    const float* x = (const float*)d_in[0];
    float* out = (float*)d_out;
    const int total = NB * (HW / 2);      // 131072 threads
    const int block = 256;
    const int grid = total / block;       // 512 blocks
    ema_kernel<<<grid, block, 0, stream>>>(x, out);
}

// Round 2
// 14.689 us; speedup vs baseline: 1.0034x; 1.0034x over previous
//
#include <hip/hip_runtime.h>

// x: (16, 48, 10, 128, 128) f32.  out: (16, 10, 128, 128) f32.
// out[b,k,h,w] = p_k * LA(b,h,w) + q_k * x[b,47,0,h,w]
// LA = (1-mu)^48 * mean_t(x_t) + mu * sum_t (1-mu)^(47-t) x_t   (feature 0 only)
//
// Lane-pair split: even lane accumulates t=0..23, odd lane t=24..47 of the
// SAME float4 pixel group; combine with __shfl_xor(1). float4 loads (16B/lane).

#define NB 16
#define NT 48
#define NF 10
#define HW (128 * 128)
#define NK 10
#define HALF 24

struct Coefs {
    float w[NT];
    float p[NK];
    float q[NK];
};

constexpr Coefs make_coefs() {
    Coefs c{};
    const double mu = 2.0 / 11.0;
    const double om = 1.0 - mu;
    double pow48 = 1.0;
    for (int i = 0; i < NT; ++i) pow48 *= om;
    for (int t = 0; t < NT; ++t) {
        double e = 1.0;
        for (int i = 0; i < NT - 1 - t; ++i) e *= om;   // (1-mu)^(47-t)
        c.w[t] = (float)(pow48 / (double)NT + mu * e);
    }
    // a_{-1}=x47 (p=0,q=1), a_0=LA (p=1,q=0); a_{k+1}=mu*a_{k-1}+(1-mu)*a_k
    double pm1 = 0.0, p0 = 1.0, qm1 = 1.0, q0 = 0.0;
    for (int k = 0; k < NK; ++k) {
        c.p[k] = (float)p0;
        c.q[k] = (float)q0;
        double pn = mu * pm1 + om * p0;
        double qn = mu * qm1 + om * q0;
        pm1 = p0; p0 = pn;
        qm1 = q0; q0 = qn;
    }
    return c;
}

constexpr Coefs CO = make_coefs();

__global__ __launch_bounds__(256) void ema_kernel(const float* __restrict__ x,
                                                  float* __restrict__ out) {
    const int tid = blockIdx.x * blockDim.x + threadIdx.x;  // 0 .. NB*HW/4*2 - 1
    const int h   = tid & 1;        // which half of the t-range
    const int p   = tid >> 1;       // float4 pixel-group id: 0 .. NB*HW/4 - 1
    const int b   = p >> 12;        // / (HW/4 = 4096)
    const int c4  = p & 4095;

    const int TS = NF * HW / 4;     // float4 stride between time planes (40960)

    const float4* xp =
        reinterpret_cast<const float4*>(x + (size_t)b * NT * NF * HW) +
        (size_t)h * HALF * TS + c4;

    float4 la  = make_float4(0.f, 0.f, 0.f, 0.f);
    float4 x47 = make_float4(0.f, 0.f, 0.f, 0.f);
#pragma unroll
    for (int t = 0; t < HALF; ++t) {
        float4 v = xp[(size_t)t * TS];
        const float wt = h ? CO.w[HALF + t] : CO.w[t];
        la.x = fmaf(wt, v.x, la.x);
        la.y = fmaf(wt, v.y, la.y);
        la.z = fmaf(wt, v.z, la.z);
        la.w = fmaf(wt, v.w, la.w);
        if (t == HALF - 1) {
            if (h) x47 = v;         // only odd lanes saw t=47; even keep 0
        }
    }

    // combine halves across the lane pair
    la.x += __shfl_xor(la.x, 1);
    la.y += __shfl_xor(la.y, 1);
    la.z += __shfl_xor(la.z, 1);
    la.w += __shfl_xor(la.w, 1);
    x47.x += __shfl_xor(x47.x, 1);
    x47.y += __shfl_xor(x47.y, 1);
    x47.z += __shfl_xor(x47.z, 1);
    x47.w += __shfl_xor(x47.w, 1);

    // even lane writes k=0..4, odd lane writes k=5..9
    float4* op = reinterpret_cast<float4*>(out + (size_t)b * NK * HW) + c4;
#pragma unroll
    for (int j = 0; j < 5; ++j) {
        const float pk = h ? CO.p[5 + j] : CO.p[j];
        const float qk = h ? CO.q[5 + j] : CO.q[j];
        float4 o;
        o.x = fmaf(pk, la.x, qk * x47.x);
        o.y = fmaf(pk, la.y, qk * x47.y);
        o.z = fmaf(pk, la.z, qk * x47.z);
        o.w = fmaf(pk, la.w, qk * x47.w);
        op[(size_t)(h * 5 + j) * (HW / 4)] = o;
    }
}

extern "C" void kernel_launch(void* const* d_in, const int* in_sizes, int n_in,
                              void* d_out, int out_size, void* d_ws, size_t ws_size,
                              hipStream_t stream) {
    const float* x = (const float*)d_in[0];
    float* out = (float*)d_out;
    const int total = NB * (HW / 4) * 2;  // 131072 threads
    const int block = 256;
    const int grid  = total / block;      // 512 blocks
    ema_kernel<<<grid, block, 0, stream>>>(x, out);
}